// Round 5
// baseline (118.523 us; speedup 1.0000x reference)
//
#include <hip/hip_runtime.h>

// VectorQuantizer: B=32768, D=256, K=16
// out layout (all f32): [0, B*D) z_q ; [B*D] vq_loss ; [B*D+1, 2*B*D+1) indices (as float)

constexpr int Bn = 32768;
constexpr int Dn = 256;
constexpr int Kn = 16;
constexpr int NQUAD = Bn * Dn / 4;      // 2,097,152 quads
constexpr float LOSS_SCALE = 1.25f / (float)Bn;  // (1 + 0.25) * (1/B)

__global__ void vq_init_loss(float* out) {
    if (threadIdx.x == 0) out[(size_t)Bn * Dn] = 0.0f;
}

__global__ __launch_bounds__(256) void vq_main(const float* __restrict__ z,
                                               const float* __restrict__ cb,
                                               float* __restrict__ out) {
    // codebook transposed into LDS: cbt[k*Dn + d]
    __shared__ float cbt[Kn * Dn];
    __shared__ float wsum[4];
    for (int i = threadIdx.x; i < Kn * Dn; i += 256) {
        int d = i >> 4;        // codebooks is (D, K) row-major
        int k = i & (Kn - 1);
        cbt[k * Dn + d] = cb[i];
    }
    __syncthreads();

    float* __restrict__ zq   = out;
    float* __restrict__ idxf = out + (size_t)Bn * Dn + 1;

    float acc = 0.0f;
    const int stride = gridDim.x * blockDim.x;
    for (int q = blockIdx.x * blockDim.x + threadIdx.x; q < NQUAD; q += stride) {
        const int f  = q * 4;
        const int d0 = f & (Dn - 1);          // 16B-aligned within row
        const float4 zv = *reinterpret_cast<const float4*>(z + f);
        const float zz[4] = {zv.x, zv.y, zv.z, zv.w};

        float best[4] = {1e30f, 1e30f, 1e30f, 1e30f};
        float bc[4]   = {0.f, 0.f, 0.f, 0.f};
        int   bi[4]   = {0, 0, 0, 0};

        #pragma unroll
        for (int k = 0; k < Kn; ++k) {
            const float4 c = *reinterpret_cast<const float4*>(&cbt[k * Dn + d0]);
            const float cc[4] = {c.x, c.y, c.z, c.w};
            #pragma unroll
            for (int j = 0; j < 4; ++j) {
                float dd = zz[j] - cc[j];
                float d2 = dd * dd;
                bool lt = d2 < best[j];        // strict < : first-min tie-break, matches jnp.argmin
                best[j] = lt ? d2 : best[j];
                bc[j]   = lt ? cc[j] : bc[j];
                bi[j]   = lt ? k : bi[j];
            }
        }

        // z_q: aligned float4 store
        *reinterpret_cast<float4*>(zq + f) = make_float4(bc[0], bc[1], bc[2], bc[3]);

        // indices region is 4B-misaligned (starts at B*D+1): scalar stores; L2 merges lines
        idxf[f + 0] = (float)bi[0];
        idxf[f + 1] = (float)bi[1];
        idxf[f + 2] = (float)bi[2];
        idxf[f + 3] = (float)bi[3];

        // loss term per element IS the best squared distance
        acc += best[0] + best[1] + best[2] + best[3];
    }

    // wave reduce (64 lanes)
    #pragma unroll
    for (int off = 32; off > 0; off >>= 1)
        acc += __shfl_down(acc, off, 64);

    const int lane = threadIdx.x & 63;
    const int wid  = threadIdx.x >> 6;
    if (lane == 0) wsum[wid] = acc;
    __syncthreads();
    if (threadIdx.x == 0) {
        float s = (wsum[0] + wsum[1] + wsum[2] + wsum[3]) * LOSS_SCALE;
        atomicAdd(out + (size_t)Bn * Dn, s);
    }
}

extern "C" void kernel_launch(void* const* d_in, const int* in_sizes, int n_in,
                              void* d_out, int out_size, void* d_ws, size_t ws_size,
                              hipStream_t stream) {
    const float* z  = (const float*)d_in[0];
    const float* cb = (const float*)d_in[1];
    float* out = (float*)d_out;

    vq_init_loss<<<1, 64, 0, stream>>>(out);

    const int block = 256;
    const int grid  = 2048;   // ~8 blocks/CU worth of waves; grid-stride covers 4 quads/thread
    vq_main<<<grid, block, 0, stream>>>(z, cb, out);
}